// Round 15
// baseline (205.385 us; speedup 1.0000x reference)
//
#include <hip/hip_runtime.h>

// BusStopPredictor: 2x SAGEConv(mean) + BN(eval) + ReLU, then Linear(64->1).
// N=50000 nodes, E=800000 edges, 32 -> 64 -> 64 -> 1.
//
// Round 1: dst-sorted CSR + per-node gather (no float atomics): 1251 -> 374us.
// Round 2: node GEMMs 16-lanes-per-node: 374 -> 337us.
// Round 4: LDS weights + 4 nodes/thread; node1 full-unroll spilled: -> 371us.
// Round 5: unroll capped at 4 + gathers 2 edge-slots/node: -> 284us.
// Round 6: XCD-partitioned fill FAILED (chunk-claim barriers killed MLP).
// Round 7/9: uint16 csr + 4-slot gathers: -> 272us.
// Round 10: slice x range fill + NT: 269us (scatter write-back is structural).
// Round 11: two-pass LDS radix CSR build: 269 -> 214us.
// Round 12: fuse gather+node FAILED (255us, 18% occupancy + serial gather).
// Round 13/14: bf16-h (gather64 reads 128B/row): 214 -> 205us, absmax 0.0039.
//   Confirms gathers are BW-bound on random row reads.
// Round 15: same lever on gather32: cast x -> bf16 once (k_cast, ~3us), gather32
//   reads 64B/row (was 128B). node1 root term still reads fp32 x (no extra
//   error on that path). Single-variable change.

constexpr int NN = 50000;
constexpr int NE = 800000;
constexpr int NBLK = (NN + 63) / 64;    // 782 blocks, 64 nodes each
constexpr float BN_EPS = 1e-5f;

constexpr int NBUCK = 196;              // buckets of 256 nodes (dst>>8)
constexpr int BCAP  = 8192;             // per-bucket capacity (avg 4082)
constexpr int APB   = 2048;             // edges per pass-A block
constexpr int NAB   = (NE + APB - 1) / APB;  // 391

// fp32 -> bf16, round-to-nearest-even
__device__ __forceinline__ unsigned short f2bf(float f) {
    union { float f; unsigned int u; } c; c.f = f;
    unsigned int lsb = (c.u >> 16) & 1u;
    c.u += 0x7fffu + lsb;
    return (unsigned short)(c.u >> 16);
}

// ---------------- cast x (fp32) -> xb (bf16) ----------------
// 1.6M elements; each thread converts 8 (two float4 -> one ushort8 store).
__global__ __launch_bounds__(256) void k_cast(const float* __restrict__ x,
                                              unsigned short* __restrict__ xb) {
    int i = (blockIdx.x * 256 + threadIdx.x) * 8;
    if (i >= NN * 32) return;
    float4 a = *(const float4*)(x + i);
    float4 b = *(const float4*)(x + i + 4);
    ushort4 r0, r1;
    r0.x = f2bf(a.x); r0.y = f2bf(a.y); r0.z = f2bf(a.z); r0.w = f2bf(a.w);
    r1.x = f2bf(b.x); r1.y = f2bf(b.y); r1.z = f2bf(b.z); r1.w = f2bf(b.w);
    *(ushort4*)(xb + i) = r0;
    *(ushort4*)(xb + i + 4) = r1;
}

// ---------------- pass A: bin edges by dst>>8 ----------------
__global__ __launch_bounds__(256) void k_binA(const int* __restrict__ ei,
                                              int* __restrict__ cursor,
                                              unsigned int* __restrict__ region) {
    __shared__ int lcnt[NBUCK];
    __shared__ int gb[NBUCK];
    int tid = threadIdx.x;
    for (int i = tid; i < NBUCK; i += 256) lcnt[i] = 0;
    __syncthreads();
    int e0 = blockIdx.x * APB;
    unsigned int pk[8];
    int bk[8], rk[8];
#pragma unroll
    for (int i = 0; i < 8; i++) {
        int e = e0 + i * 256 + tid;
        bk[i] = -1;
        if (e < NE) {
            int s = ei[e];
            int d = ei[NE + e];
            pk[i] = ((unsigned int)d << 16) | (unsigned int)s;
            bk[i] = d >> 8;
            rk[i] = atomicAdd(&lcnt[bk[i]], 1);
        }
    }
    __syncthreads();
    if (tid < NBUCK && lcnt[tid] > 0) gb[tid] = atomicAdd(&cursor[tid], lcnt[tid]);
    __syncthreads();
#pragma unroll
    for (int i = 0; i < 8; i++) {
        if (bk[i] >= 0) region[bk[i] * BCAP + gb[bk[i]] + rk[i]] = pk[i];
    }
}

// ---------------- pass B: build csr segment per bucket ----------------
__global__ __launch_bounds__(256) void k_binB(const int* __restrict__ cursor,
                                              const unsigned int* __restrict__ region,
                                              int* __restrict__ deg_i,
                                              int* __restrict__ base,
                                              unsigned short* __restrict__ csr16) {
    __shared__ unsigned int stg[BCAP];   // 32KB
    __shared__ int lc[256], cur[256], sctmp[256];
    int tid = threadIdx.x;
    int b = blockIdx.x;

    int cntt = (tid < NBUCK) ? cursor[tid] : 0;
    sctmp[tid] = cntt;
    __syncthreads();
    for (int off = 1; off < 256; off <<= 1) {
        int t = (tid >= off) ? sctmp[tid - off] : 0;
        __syncthreads();
        sctmp[tid] += t;
        __syncthreads();
    }
    int B0 = (b == 0) ? 0 : sctmp[b - 1];
    int mycnt = cursor[b];

    for (int k = tid; k < mycnt; k += 256) stg[k] = region[b * BCAP + k];
    lc[tid] = 0;
    __syncthreads();

    int node0 = b << 8;
    for (int k = tid; k < mycnt; k += 256) {
        int local = (int)(stg[k] >> 16) - node0;
        atomicAdd(&lc[local], 1);
    }
    __syncthreads();

    int myc = lc[tid];
    sctmp[tid] = myc;
    __syncthreads();
    for (int off = 1; off < 256; off <<= 1) {
        int t = (tid >= off) ? sctmp[tid - off] : 0;
        __syncthreads();
        sctmp[tid] += t;
        __syncthreads();
    }
    int myoff = sctmp[tid] - myc;
    cur[tid] = myoff;
    int n = node0 + tid;
    if (n < NN) {
        deg_i[n] = myc;
        base[n] = B0 + myoff + myc;   // row_end (gather contract)
    }
    __syncthreads();

    for (int k = tid; k < mycnt; k += 256) {
        unsigned int p = stg[k];
        int local = (int)(p >> 16) - node0;
        int pos = atomicAdd(&cur[local], 1);
        csr16[B0 + pos] = (unsigned short)(p & 0xffffu);
    }
}

// ---------------- gather aggregation, 32 channels (xb bf16) ----------------
// 32 lanes per node: 4 edge-slots x 8 channel-lanes (4 ch each).
// Per edge: 8 lanes x uint2 (8B = 4 bf16) = 64B coalesced row read.
__global__ __launch_bounds__(256) void k_gather32(const unsigned short* __restrict__ csr_src,
                                                  const int* __restrict__ base,
                                                  const int* __restrict__ deg_i,
                                                  const unsigned short* __restrict__ xb,
                                                  float* __restrict__ agg) {
    int t = blockIdx.x * 256 + threadIdx.x;
    int n = t >> 5;
    if (n >= NN) return;
    int p = (t >> 3) & 3;            // edge slot 0..3
    int c4 = (t & 7) << 2;           // channel offset
    int end = base[n];
    int st = end - deg_i[n];
    float4 acc = make_float4(0.f, 0.f, 0.f, 0.f);
    for (int e = st + p; e < end; e += 4) {
        int s = csr_src[e];
        uint2 v = *(const uint2*)(xb + (size_t)s * 32 + c4);
        acc.x += __uint_as_float(v.x << 16);
        acc.y += __uint_as_float(v.x & 0xffff0000u);
        acc.z += __uint_as_float(v.y << 16);
        acc.w += __uint_as_float(v.y & 0xffff0000u);
    }
    acc.x += __shfl_xor(acc.x, 8, 64);
    acc.y += __shfl_xor(acc.y, 8, 64);
    acc.z += __shfl_xor(acc.z, 8, 64);
    acc.w += __shfl_xor(acc.w, 8, 64);
    acc.x += __shfl_xor(acc.x, 16, 64);
    acc.y += __shfl_xor(acc.y, 16, 64);
    acc.z += __shfl_xor(acc.z, 16, 64);
    acc.w += __shfl_xor(acc.w, 16, 64);
    if (p == 0) *(float4*)(agg + (size_t)n * 32 + c4) = acc;
}

// ---------------- gather aggregation, 64 channels (h bf16) ----------------
// 64 lanes (full wave) per node: 4 edge-slots x 16 channel-lanes (4 ch each).
// Per edge: 16 lanes x uint2 (8B = 4 bf16) = 128B coalesced row read.
__global__ __launch_bounds__(256) void k_gather64(const unsigned short* __restrict__ csr_src,
                                                  const int* __restrict__ base,
                                                  const int* __restrict__ deg_i,
                                                  const unsigned short* __restrict__ h,
                                                  float* __restrict__ agg) {
    int t = blockIdx.x * 256 + threadIdx.x;
    int n = t >> 6;
    if (n >= NN) return;
    int p = (t >> 4) & 3;            // edge slot 0..3
    int c4 = (t & 15) << 2;          // channel offset
    int end = base[n];
    int st = end - deg_i[n];
    float4 acc = make_float4(0.f, 0.f, 0.f, 0.f);
    for (int e = st + p; e < end; e += 4) {
        int s = csr_src[e];
        uint2 v = *(const uint2*)(h + (size_t)s * 64 + c4);
        acc.x += __uint_as_float(v.x << 16);
        acc.y += __uint_as_float(v.x & 0xffff0000u);
        acc.z += __uint_as_float(v.y << 16);
        acc.w += __uint_as_float(v.y & 0xffff0000u);
    }
    acc.x += __shfl_xor(acc.x, 16, 64);
    acc.y += __shfl_xor(acc.y, 16, 64);
    acc.z += __shfl_xor(acc.z, 16, 64);
    acc.w += __shfl_xor(acc.w, 16, 64);
    acc.x += __shfl_xor(acc.x, 32, 64);
    acc.y += __shfl_xor(acc.y, 32, 64);
    acc.z += __shfl_xor(acc.z, 32, 64);
    acc.w += __shfl_xor(acc.w, 32, 64);
    if (p == 0) *(float4*)(agg + (size_t)n * 64 + c4) = acc;
}

// ---------------- node update layer 1 -> h (bf16) ----------------
// h = relu(bn1(agg*deg_inv @ W1l + b1l + x @ W1r))
// Root term reads fp32 x (no bf16 error on that path).
__global__ __launch_bounds__(256) void k_node1(
    const float* __restrict__ x, const float* __restrict__ agg,
    const int* __restrict__ deg_i,
    const float* __restrict__ W1l, const float* __restrict__ b1l,
    const float* __restrict__ W1r,
    const float* __restrict__ g1, const float* __restrict__ bb1,
    const float* __restrict__ m1, const float* __restrict__ v1,
    unsigned short* __restrict__ h) {
    __shared__ float wlds[32 * 128];
    int tid = threadIdx.x;
    {
        const float4* l4 = (const float4*)W1l;   // 512 float4
        const float4* r4 = (const float4*)W1r;
        float4* s4 = (float4*)wlds;
#pragma unroll
        for (int i = 0; i < 2; i++) {
            int idx = tid + i * 256;
            int k = idx >> 4, c = idx & 15;
            s4[k * 32 + c] = l4[idx];
            s4[k * 32 + 16 + c] = r4[idx];
        }
    }
    __syncthreads();

    int lg = tid & 15, o4 = lg << 2;
    int nbase = blockIdx.x * 64 + (tid >> 4) * 4;
    if (nbase >= NN) return;

    float4 acc[4];
    float di[4];
    int nj[4];
#pragma unroll
    for (int j = 0; j < 4; j++) {
        acc[j] = make_float4(0.f, 0.f, 0.f, 0.f);
        nj[j] = min(nbase + j, NN - 1);   // clamp: loads stay in-bounds
        di[j] = 1.0f / fmaxf((float)deg_i[nj[j]], 1.0f);
    }

#pragma unroll 4
    for (int i4 = 0; i4 < 32; i4 += 4) {
        float4 wl[4], wr[4];
#pragma unroll
        for (int k = 0; k < 4; k++) {
            wl[k] = *(const float4*)&wlds[(i4 + k) * 128 + o4];
            wr[k] = *(const float4*)&wlds[(i4 + k) * 128 + 64 + o4];
        }
#pragma unroll
        for (int j = 0; j < 4; j++) {
            float4 a4 = *(const float4*)(agg + (size_t)nj[j] * 32 + i4);
            float4 x4 = *(const float4*)(x + (size_t)nj[j] * 32 + i4);
            float av[4] = {a4.x * di[j], a4.y * di[j], a4.z * di[j], a4.w * di[j]};
            float xv[4] = {x4.x, x4.y, x4.z, x4.w};
#pragma unroll
            for (int k = 0; k < 4; k++) {
                acc[j].x += av[k] * wl[k].x + xv[k] * wr[k].x;
                acc[j].y += av[k] * wl[k].y + xv[k] * wr[k].y;
                acc[j].z += av[k] * wl[k].z + xv[k] * wr[k].z;
                acc[j].w += av[k] * wl[k].w + xv[k] * wr[k].w;
            }
        }
    }

    float4 bl = *(const float4*)(b1l + o4);
    float4 gg = *(const float4*)(g1 + o4);
    float4 bb = *(const float4*)(bb1 + o4);
    float4 mm = *(const float4*)(m1 + o4);
    float4 vv = *(const float4*)(v1 + o4);
    float4 sc;
    sc.x = gg.x * rsqrtf(vv.x + BN_EPS);
    sc.y = gg.y * rsqrtf(vv.y + BN_EPS);
    sc.z = gg.z * rsqrtf(vv.z + BN_EPS);
    sc.w = gg.w * rsqrtf(vv.w + BN_EPS);
#pragma unroll
    for (int j = 0; j < 4; j++) {
        if (nbase + j >= NN) break;
        ushort4 r;
        r.x = f2bf(fmaxf((acc[j].x + bl.x - mm.x) * sc.x + bb.x, 0.0f));
        r.y = f2bf(fmaxf((acc[j].y + bl.y - mm.y) * sc.y + bb.y, 0.0f));
        r.z = f2bf(fmaxf((acc[j].z + bl.z - mm.z) * sc.z + bb.z, 0.0f));
        r.w = f2bf(fmaxf((acc[j].w + bl.w - mm.w) * sc.w + bb.w, 0.0f));
        *(ushort4*)(h + (size_t)(nbase + j) * 64 + o4) = r;
    }
}

// ---------------- node update layer 2 + final linear ----------------
// out = relu(bn2(agg*deg_inv @ W2l + b2l + h @ W2r)) @ Wlin + blin
// h roots read as bf16 (uint2 per 4 channels).
__global__ __launch_bounds__(256) void k_node2(
    const unsigned short* __restrict__ h, const float* __restrict__ agg,
    const int* __restrict__ deg_i,
    const float* __restrict__ W2l, const float* __restrict__ b2l,
    const float* __restrict__ W2r,
    const float* __restrict__ g2, const float* __restrict__ bb2,
    const float* __restrict__ m2, const float* __restrict__ v2,
    const float* __restrict__ Wlin, const float* __restrict__ blin,
    float* __restrict__ out) {
    __shared__ float wlds[64 * 128];
    int tid = threadIdx.x;
    {
        const float4* l4 = (const float4*)W2l;   // 1024 float4
        const float4* r4 = (const float4*)W2r;
        float4* s4 = (float4*)wlds;
#pragma unroll
        for (int i = 0; i < 4; i++) {
            int idx = tid + i * 256;
            int k = idx >> 4, c = idx & 15;
            s4[k * 32 + c] = l4[idx];
            s4[k * 32 + 16 + c] = r4[idx];
        }
    }
    __syncthreads();

    int lg = tid & 15, o4 = lg << 2;
    int nbase = blockIdx.x * 64 + (tid >> 4) * 4;
    if (nbase >= NN) return;

    float4 acc[4];
    float di[4];
    int nj[4];
#pragma unroll
    for (int j = 0; j < 4; j++) {
        acc[j] = make_float4(0.f, 0.f, 0.f, 0.f);
        nj[j] = min(nbase + j, NN - 1);
        di[j] = 1.0f / fmaxf((float)deg_i[nj[j]], 1.0f);
    }

#pragma unroll 4
    for (int i4 = 0; i4 < 64; i4 += 4) {
        float4 wl[4], wr[4];
#pragma unroll
        for (int k = 0; k < 4; k++) {
            wl[k] = *(const float4*)&wlds[(i4 + k) * 128 + o4];
            wr[k] = *(const float4*)&wlds[(i4 + k) * 128 + 64 + o4];
        }
#pragma unroll
        for (int j = 0; j < 4; j++) {
            float4 a4 = *(const float4*)(agg + (size_t)nj[j] * 64 + i4);
            uint2 hu = *(const uint2*)(h + (size_t)nj[j] * 64 + i4);
            float av[4] = {a4.x * di[j], a4.y * di[j], a4.z * di[j], a4.w * di[j]};
            float hv[4];
            hv[0] = __uint_as_float(hu.x << 16);
            hv[1] = __uint_as_float(hu.x & 0xffff0000u);
            hv[2] = __uint_as_float(hu.y << 16);
            hv[3] = __uint_as_float(hu.y & 0xffff0000u);
#pragma unroll
            for (int k = 0; k < 4; k++) {
                acc[j].x += av[k] * wl[k].x + hv[k] * wr[k].x;
                acc[j].y += av[k] * wl[k].y + hv[k] * wr[k].y;
                acc[j].z += av[k] * wl[k].z + hv[k] * wr[k].z;
                acc[j].w += av[k] * wl[k].w + hv[k] * wr[k].w;
            }
        }
    }

    float4 bl = *(const float4*)(b2l + o4);
    float4 gg = *(const float4*)(g2 + o4);
    float4 bb = *(const float4*)(bb2 + o4);
    float4 mm = *(const float4*)(m2 + o4);
    float4 vv = *(const float4*)(v2 + o4);
    float4 wo = *(const float4*)(Wlin + o4);
    float blin0 = blin[0];
    float4 sc;
    sc.x = gg.x * rsqrtf(vv.x + BN_EPS);
    sc.y = gg.y * rsqrtf(vv.y + BN_EPS);
    sc.z = gg.z * rsqrtf(vv.z + BN_EPS);
    sc.w = gg.w * rsqrtf(vv.w + BN_EPS);
#pragma unroll
    for (int j = 0; j < 4; j++) {
        float vx = fmaxf((acc[j].x + bl.x - mm.x) * sc.x + bb.x, 0.0f);
        float vy = fmaxf((acc[j].y + bl.y - mm.y) * sc.y + bb.y, 0.0f);
        float vz = fmaxf((acc[j].z + bl.z - mm.z) * sc.z + bb.z, 0.0f);
        float vw = fmaxf((acc[j].w + bl.w - mm.w) * sc.w + bb.w, 0.0f);
        float part = vx * wo.x + vy * wo.y + vz * wo.z + vw * wo.w;
#pragma unroll
        for (int m = 1; m < 16; m <<= 1) part += __shfl_xor(part, m, 64);
        if (lg == 0 && nbase + j < NN) out[nbase + j] = part + blin0;
    }
}

extern "C" void kernel_launch(void* const* d_in, const int* in_sizes, int n_in,
                              void* d_out, int out_size, void* d_ws, size_t ws_size,
                              hipStream_t stream) {
    const float* x    = (const float*)d_in[0];
    const int*   ei   = (const int*)d_in[1];
    const float* W1l  = (const float*)d_in[2];
    const float* b1l  = (const float*)d_in[3];
    const float* W1r  = (const float*)d_in[4];
    const float* g1   = (const float*)d_in[5];
    const float* bb1  = (const float*)d_in[6];
    const float* m1   = (const float*)d_in[7];
    const float* v1   = (const float*)d_in[8];
    const float* W2l  = (const float*)d_in[9];
    const float* b2l  = (const float*)d_in[10];
    const float* W2r  = (const float*)d_in[11];
    const float* g2   = (const float*)d_in[12];
    const float* bb2  = (const float*)d_in[13];
    const float* m2   = (const float*)d_in[14];
    const float* v2   = (const float*)d_in[15];
    const float* Wlin = (const float*)d_in[16];
    const float* blin = (const float*)d_in[17];
    float* out = (float*)d_out;

    // ws layout:
    //   cursor  int[256]          per-bucket claim cursors (only [0,196) used)
    //   region  u32[196*8192]     binned packed edges (6.4MB)
    //   deg_i   int[N]            degree per dst node (written by pass B)
    //   base    int[N]            row_end per node (written by pass B)
    //   csr16   ushort[E]         src indices sorted by dst
    //   agg     float[64N]        aggregation buffer (reused both layers)
    //   h       bf16[64N]         layer-1 output (6.4MB)
    //   xb      bf16[32N]         x cast to bf16 (3.2MB)
    int* cursor = (int*)d_ws;
    unsigned int* region = (unsigned int*)(cursor + 256);
    int* deg_i = (int*)(region + (size_t)NBUCK * BCAP);
    int* base  = deg_i + NN;
    unsigned short* csr16 = (unsigned short*)(base + NN);
    float* agg = (float*)(csr16 + NE);
    unsigned short* h = (unsigned short*)(agg + (size_t)64 * NN);
    unsigned short* xb = h + (size_t)64 * NN;

    // only the bucket cursors need zeroing (1KB)
    hipMemsetAsync(cursor, 0, 256 * sizeof(int), stream);

    k_cast<<<(NN * 32 / 8 + 255) / 256, 256, 0, stream>>>(x, xb);
    k_binA<<<NAB, 256, 0, stream>>>(ei, cursor, region);
    k_binB<<<NBUCK, 256, 0, stream>>>(cursor, region, deg_i, base, csr16);

    k_gather32<<<(NN * 32 + 255) / 256, 256, 0, stream>>>(csr16, base, deg_i, xb, agg);
    k_node1<<<NBLK, 256, 0, stream>>>(x, agg, deg_i, W1l, b1l, W1r,
                                      g1, bb1, m1, v1, h);
    k_gather64<<<(NN * 64 + 255) / 256, 256, 0, stream>>>(csr16, base, deg_i, h, agg);
    k_node2<<<NBLK, 256, 0, stream>>>(h, agg, deg_i, W2l, b2l, W2r,
                                      g2, bb2, m2, v2, Wlin, blin, out);
}

// Round 16
// 202.796 us; speedup vs baseline: 1.0128x; 1.0128x over previous
//
#include <hip/hip_runtime.h>

// BusStopPredictor: 2x SAGEConv(mean) + BN(eval) + ReLU, then Linear(64->1).
// N=50000 nodes, E=800000 edges, 32 -> 64 -> 64 -> 1.
//
// Round 1: dst-sorted CSR + per-node gather (no float atomics): 1251 -> 374us.
// Round 2: node GEMMs 16-lanes-per-node: 374 -> 337us.
// Round 4: LDS weights + 4 nodes/thread; node1 full-unroll spilled: -> 371us.
// Round 5: unroll capped at 4 + gathers 2 edge-slots/node: -> 284us.
// Round 6: XCD-partitioned fill FAILED (chunk-claim barriers killed MLP).
// Round 7/9: uint16 csr + 4-slot gathers: -> 272us.
// Round 10: slice x range fill + NT: 269us (scatter write-back is structural).
// Round 11: two-pass LDS radix CSR build: 269 -> 214us.
// Round 12: fuse gather+node FAILED (255us, 18% occupancy + serial gather).
// Round 13/14: bf16-h (gather64 rows 256->128B): 214 -> 205us. h spills L2,
//   so byte-halving its random reads pays.
// Round 15: bf16-x gather32 NEUTRAL (205us): x fits L2, reads were already
//   hits; k_cast dispatch cost cancelled the gain.
// Round 16: (a) fuse cast into binA (disjoint block ranges) - recovers the
//   cast cost by overlapping it, -1 dispatch. (b) agg stored bf16: 38.4 ->
//   19.2 MB of sequential write-back+re-read across both layers.

constexpr int NN = 50000;
constexpr int NE = 800000;
constexpr int NBLK = (NN + 63) / 64;    // 782 blocks, 64 nodes each
constexpr float BN_EPS = 1e-5f;

constexpr int NBUCK = 196;              // buckets of 256 nodes (dst>>8)
constexpr int BCAP  = 8192;             // per-bucket capacity (avg 4082)
constexpr int APB   = 2048;             // edges per pass-A block
constexpr int NAB   = (NE + APB - 1) / APB;  // 391
constexpr int CASTB = (NN * 32 / 8 + 255) / 256;  // 782 cast blocks

// fp32 -> bf16, round-to-nearest-even
__device__ __forceinline__ unsigned short f2bf(float f) {
    union { float f; unsigned int u; } c; c.f = f;
    unsigned int lsb = (c.u >> 16) & 1u;
    c.u += 0x7fffu + lsb;
    return (unsigned short)(c.u >> 16);
}

// ---------------- pass A: bin edges by dst>>8, + cast x->bf16 ----------------
// Blocks [0,NAB): bin packed (dst<<16|src) into per-bucket regions.
// Blocks [NAB,NAB+CASTB): cast x (fp32) -> xb (bf16), 8 elems/thread.
// The two roles are data-independent; fusing overlaps the cast under binA.
__global__ __launch_bounds__(256) void k_binA_cast(const int* __restrict__ ei,
                                                   int* __restrict__ cursor,
                                                   unsigned int* __restrict__ region,
                                                   const float* __restrict__ x,
                                                   unsigned short* __restrict__ xb) {
    __shared__ int lcnt[NBUCK];
    __shared__ int gb[NBUCK];
    int tid = threadIdx.x;

    if (blockIdx.x >= NAB) {   // cast role
        int i = ((blockIdx.x - NAB) * 256 + tid) * 8;
        if (i < NN * 32) {
            float4 a = *(const float4*)(x + i);
            float4 b = *(const float4*)(x + i + 4);
            ushort4 r0, r1;
            r0.x = f2bf(a.x); r0.y = f2bf(a.y); r0.z = f2bf(a.z); r0.w = f2bf(a.w);
            r1.x = f2bf(b.x); r1.y = f2bf(b.y); r1.z = f2bf(b.z); r1.w = f2bf(b.w);
            *(ushort4*)(xb + i) = r0;
            *(ushort4*)(xb + i + 4) = r1;
        }
        return;
    }

    for (int i = tid; i < NBUCK; i += 256) lcnt[i] = 0;
    __syncthreads();
    int e0 = blockIdx.x * APB;
    unsigned int pk[8];
    int bk[8], rk[8];
#pragma unroll
    for (int i = 0; i < 8; i++) {
        int e = e0 + i * 256 + tid;
        bk[i] = -1;
        if (e < NE) {
            int s = ei[e];
            int d = ei[NE + e];
            pk[i] = ((unsigned int)d << 16) | (unsigned int)s;
            bk[i] = d >> 8;
            rk[i] = atomicAdd(&lcnt[bk[i]], 1);
        }
    }
    __syncthreads();
    if (tid < NBUCK && lcnt[tid] > 0) gb[tid] = atomicAdd(&cursor[tid], lcnt[tid]);
    __syncthreads();
#pragma unroll
    for (int i = 0; i < 8; i++) {
        if (bk[i] >= 0) region[bk[i] * BCAP + gb[bk[i]] + rk[i]] = pk[i];
    }
}

// ---------------- pass B: build csr segment per bucket ----------------
__global__ __launch_bounds__(256) void k_binB(const int* __restrict__ cursor,
                                              const unsigned int* __restrict__ region,
                                              int* __restrict__ deg_i,
                                              int* __restrict__ base,
                                              unsigned short* __restrict__ csr16) {
    __shared__ unsigned int stg[BCAP];   // 32KB
    __shared__ int lc[256], cur[256], sctmp[256];
    int tid = threadIdx.x;
    int b = blockIdx.x;

    int cntt = (tid < NBUCK) ? cursor[tid] : 0;
    sctmp[tid] = cntt;
    __syncthreads();
    for (int off = 1; off < 256; off <<= 1) {
        int t = (tid >= off) ? sctmp[tid - off] : 0;
        __syncthreads();
        sctmp[tid] += t;
        __syncthreads();
    }
    int B0 = (b == 0) ? 0 : sctmp[b - 1];
    int mycnt = cursor[b];

    for (int k = tid; k < mycnt; k += 256) stg[k] = region[b * BCAP + k];
    lc[tid] = 0;
    __syncthreads();

    int node0 = b << 8;
    for (int k = tid; k < mycnt; k += 256) {
        int local = (int)(stg[k] >> 16) - node0;
        atomicAdd(&lc[local], 1);
    }
    __syncthreads();

    int myc = lc[tid];
    sctmp[tid] = myc;
    __syncthreads();
    for (int off = 1; off < 256; off <<= 1) {
        int t = (tid >= off) ? sctmp[tid - off] : 0;
        __syncthreads();
        sctmp[tid] += t;
        __syncthreads();
    }
    int myoff = sctmp[tid] - myc;
    cur[tid] = myoff;
    int n = node0 + tid;
    if (n < NN) {
        deg_i[n] = myc;
        base[n] = B0 + myoff + myc;   // row_end (gather contract)
    }
    __syncthreads();

    for (int k = tid; k < mycnt; k += 256) {
        unsigned int p = stg[k];
        int local = (int)(p >> 16) - node0;
        int pos = atomicAdd(&cur[local], 1);
        csr16[B0 + pos] = (unsigned short)(p & 0xffffu);
    }
}

// ---------------- gather aggregation, 32 channels (xb bf16 -> aggb bf16) ----
// 32 lanes per node: 4 edge-slots x 8 channel-lanes (4 ch each).
__global__ __launch_bounds__(256) void k_gather32(const unsigned short* __restrict__ csr_src,
                                                  const int* __restrict__ base,
                                                  const int* __restrict__ deg_i,
                                                  const unsigned short* __restrict__ xb,
                                                  unsigned short* __restrict__ aggb) {
    int t = blockIdx.x * 256 + threadIdx.x;
    int n = t >> 5;
    if (n >= NN) return;
    int p = (t >> 3) & 3;            // edge slot 0..3
    int c4 = (t & 7) << 2;           // channel offset
    int end = base[n];
    int st = end - deg_i[n];
    float4 acc = make_float4(0.f, 0.f, 0.f, 0.f);
    for (int e = st + p; e < end; e += 4) {
        int s = csr_src[e];
        uint2 v = *(const uint2*)(xb + (size_t)s * 32 + c4);
        acc.x += __uint_as_float(v.x << 16);
        acc.y += __uint_as_float(v.x & 0xffff0000u);
        acc.z += __uint_as_float(v.y << 16);
        acc.w += __uint_as_float(v.y & 0xffff0000u);
    }
    acc.x += __shfl_xor(acc.x, 8, 64);
    acc.y += __shfl_xor(acc.y, 8, 64);
    acc.z += __shfl_xor(acc.z, 8, 64);
    acc.w += __shfl_xor(acc.w, 8, 64);
    acc.x += __shfl_xor(acc.x, 16, 64);
    acc.y += __shfl_xor(acc.y, 16, 64);
    acc.z += __shfl_xor(acc.z, 16, 64);
    acc.w += __shfl_xor(acc.w, 16, 64);
    if (p == 0) {
        ushort4 r;
        r.x = f2bf(acc.x); r.y = f2bf(acc.y); r.z = f2bf(acc.z); r.w = f2bf(acc.w);
        *(ushort4*)(aggb + (size_t)n * 32 + c4) = r;
    }
}

// ---------------- gather aggregation, 64 channels (h bf16 -> aggb bf16) ----
// 64 lanes (full wave) per node: 4 edge-slots x 16 channel-lanes (4 ch each).
__global__ __launch_bounds__(256) void k_gather64(const unsigned short* __restrict__ csr_src,
                                                  const int* __restrict__ base,
                                                  const int* __restrict__ deg_i,
                                                  const unsigned short* __restrict__ h,
                                                  unsigned short* __restrict__ aggb) {
    int t = blockIdx.x * 256 + threadIdx.x;
    int n = t >> 6;
    if (n >= NN) return;
    int p = (t >> 4) & 3;            // edge slot 0..3
    int c4 = (t & 15) << 2;          // channel offset
    int end = base[n];
    int st = end - deg_i[n];
    float4 acc = make_float4(0.f, 0.f, 0.f, 0.f);
    for (int e = st + p; e < end; e += 4) {
        int s = csr_src[e];
        uint2 v = *(const uint2*)(h + (size_t)s * 64 + c4);
        acc.x += __uint_as_float(v.x << 16);
        acc.y += __uint_as_float(v.x & 0xffff0000u);
        acc.z += __uint_as_float(v.y << 16);
        acc.w += __uint_as_float(v.y & 0xffff0000u);
    }
    acc.x += __shfl_xor(acc.x, 16, 64);
    acc.y += __shfl_xor(acc.y, 16, 64);
    acc.z += __shfl_xor(acc.z, 16, 64);
    acc.w += __shfl_xor(acc.w, 16, 64);
    acc.x += __shfl_xor(acc.x, 32, 64);
    acc.y += __shfl_xor(acc.y, 32, 64);
    acc.z += __shfl_xor(acc.z, 32, 64);
    acc.w += __shfl_xor(acc.w, 32, 64);
    if (p == 0) {
        ushort4 r;
        r.x = f2bf(acc.x); r.y = f2bf(acc.y); r.z = f2bf(acc.z); r.w = f2bf(acc.w);
        *(ushort4*)(aggb + (size_t)n * 64 + c4) = r;
    }
}

// ---------------- node update layer 1 -> h (bf16) ----------------
// h = relu(bn1(aggb*deg_inv @ W1l + b1l + x @ W1r))
// Root term reads fp32 x (no bf16 error on that path). aggb read as bf16.
__global__ __launch_bounds__(256) void k_node1(
    const float* __restrict__ x, const unsigned short* __restrict__ aggb,
    const int* __restrict__ deg_i,
    const float* __restrict__ W1l, const float* __restrict__ b1l,
    const float* __restrict__ W1r,
    const float* __restrict__ g1, const float* __restrict__ bb1,
    const float* __restrict__ m1, const float* __restrict__ v1,
    unsigned short* __restrict__ h) {
    __shared__ float wlds[32 * 128];
    int tid = threadIdx.x;
    {
        const float4* l4 = (const float4*)W1l;   // 512 float4
        const float4* r4 = (const float4*)W1r;
        float4* s4 = (float4*)wlds;
#pragma unroll
        for (int i = 0; i < 2; i++) {
            int idx = tid + i * 256;
            int k = idx >> 4, c = idx & 15;
            s4[k * 32 + c] = l4[idx];
            s4[k * 32 + 16 + c] = r4[idx];
        }
    }
    __syncthreads();

    int lg = tid & 15, o4 = lg << 2;
    int nbase = blockIdx.x * 64 + (tid >> 4) * 4;
    if (nbase >= NN) return;

    float4 acc[4];
    float di[4];
    int nj[4];
#pragma unroll
    for (int j = 0; j < 4; j++) {
        acc[j] = make_float4(0.f, 0.f, 0.f, 0.f);
        nj[j] = min(nbase + j, NN - 1);   // clamp: loads stay in-bounds
        di[j] = 1.0f / fmaxf((float)deg_i[nj[j]], 1.0f);
    }

#pragma unroll 4
    for (int i4 = 0; i4 < 32; i4 += 4) {
        float4 wl[4], wr[4];
#pragma unroll
        for (int k = 0; k < 4; k++) {
            wl[k] = *(const float4*)&wlds[(i4 + k) * 128 + o4];
            wr[k] = *(const float4*)&wlds[(i4 + k) * 128 + 64 + o4];
        }
#pragma unroll
        for (int j = 0; j < 4; j++) {
            uint2 au = *(const uint2*)(aggb + (size_t)nj[j] * 32 + i4);
            float4 x4 = *(const float4*)(x + (size_t)nj[j] * 32 + i4);
            float av[4];
            av[0] = __uint_as_float(au.x << 16) * di[j];
            av[1] = __uint_as_float(au.x & 0xffff0000u) * di[j];
            av[2] = __uint_as_float(au.y << 16) * di[j];
            av[3] = __uint_as_float(au.y & 0xffff0000u) * di[j];
            float xv[4] = {x4.x, x4.y, x4.z, x4.w};
#pragma unroll
            for (int k = 0; k < 4; k++) {
                acc[j].x += av[k] * wl[k].x + xv[k] * wr[k].x;
                acc[j].y += av[k] * wl[k].y + xv[k] * wr[k].y;
                acc[j].z += av[k] * wl[k].z + xv[k] * wr[k].z;
                acc[j].w += av[k] * wl[k].w + xv[k] * wr[k].w;
            }
        }
    }

    float4 bl = *(const float4*)(b1l + o4);
    float4 gg = *(const float4*)(g1 + o4);
    float4 bb = *(const float4*)(bb1 + o4);
    float4 mm = *(const float4*)(m1 + o4);
    float4 vv = *(const float4*)(v1 + o4);
    float4 sc;
    sc.x = gg.x * rsqrtf(vv.x + BN_EPS);
    sc.y = gg.y * rsqrtf(vv.y + BN_EPS);
    sc.z = gg.z * rsqrtf(vv.z + BN_EPS);
    sc.w = gg.w * rsqrtf(vv.w + BN_EPS);
#pragma unroll
    for (int j = 0; j < 4; j++) {
        if (nbase + j >= NN) break;
        ushort4 r;
        r.x = f2bf(fmaxf((acc[j].x + bl.x - mm.x) * sc.x + bb.x, 0.0f));
        r.y = f2bf(fmaxf((acc[j].y + bl.y - mm.y) * sc.y + bb.y, 0.0f));
        r.z = f2bf(fmaxf((acc[j].z + bl.z - mm.z) * sc.z + bb.z, 0.0f));
        r.w = f2bf(fmaxf((acc[j].w + bl.w - mm.w) * sc.w + bb.w, 0.0f));
        *(ushort4*)(h + (size_t)(nbase + j) * 64 + o4) = r;
    }
}

// ---------------- node update layer 2 + final linear ----------------
// out = relu(bn2(aggb*deg_inv @ W2l + b2l + h @ W2r)) @ Wlin + blin
// h roots and aggb read as bf16.
__global__ __launch_bounds__(256) void k_node2(
    const unsigned short* __restrict__ h, const unsigned short* __restrict__ aggb,
    const int* __restrict__ deg_i,
    const float* __restrict__ W2l, const float* __restrict__ b2l,
    const float* __restrict__ W2r,
    const float* __restrict__ g2, const float* __restrict__ bb2,
    const float* __restrict__ m2, const float* __restrict__ v2,
    const float* __restrict__ Wlin, const float* __restrict__ blin,
    float* __restrict__ out) {
    __shared__ float wlds[64 * 128];
    int tid = threadIdx.x;
    {
        const float4* l4 = (const float4*)W2l;   // 1024 float4
        const float4* r4 = (const float4*)W2r;
        float4* s4 = (float4*)wlds;
#pragma unroll
        for (int i = 0; i < 4; i++) {
            int idx = tid + i * 256;
            int k = idx >> 4, c = idx & 15;
            s4[k * 32 + c] = l4[idx];
            s4[k * 32 + 16 + c] = r4[idx];
        }
    }
    __syncthreads();

    int lg = tid & 15, o4 = lg << 2;
    int nbase = blockIdx.x * 64 + (tid >> 4) * 4;
    if (nbase >= NN) return;

    float4 acc[4];
    float di[4];
    int nj[4];
#pragma unroll
    for (int j = 0; j < 4; j++) {
        acc[j] = make_float4(0.f, 0.f, 0.f, 0.f);
        nj[j] = min(nbase + j, NN - 1);
        di[j] = 1.0f / fmaxf((float)deg_i[nj[j]], 1.0f);
    }

#pragma unroll 4
    for (int i4 = 0; i4 < 64; i4 += 4) {
        float4 wl[4], wr[4];
#pragma unroll
        for (int k = 0; k < 4; k++) {
            wl[k] = *(const float4*)&wlds[(i4 + k) * 128 + o4];
            wr[k] = *(const float4*)&wlds[(i4 + k) * 128 + 64 + o4];
        }
#pragma unroll
        for (int j = 0; j < 4; j++) {
            uint2 au = *(const uint2*)(aggb + (size_t)nj[j] * 64 + i4);
            uint2 hu = *(const uint2*)(h + (size_t)nj[j] * 64 + i4);
            float av[4];
            av[0] = __uint_as_float(au.x << 16) * di[j];
            av[1] = __uint_as_float(au.x & 0xffff0000u) * di[j];
            av[2] = __uint_as_float(au.y << 16) * di[j];
            av[3] = __uint_as_float(au.y & 0xffff0000u) * di[j];
            float hv[4];
            hv[0] = __uint_as_float(hu.x << 16);
            hv[1] = __uint_as_float(hu.x & 0xffff0000u);
            hv[2] = __uint_as_float(hu.y << 16);
            hv[3] = __uint_as_float(hu.y & 0xffff0000u);
#pragma unroll
            for (int k = 0; k < 4; k++) {
                acc[j].x += av[k] * wl[k].x + hv[k] * wr[k].x;
                acc[j].y += av[k] * wl[k].y + hv[k] * wr[k].y;
                acc[j].z += av[k] * wl[k].z + hv[k] * wr[k].z;
                acc[j].w += av[k] * wl[k].w + hv[k] * wr[k].w;
            }
        }
    }

    float4 bl = *(const float4*)(b2l + o4);
    float4 gg = *(const float4*)(g2 + o4);
    float4 bb = *(const float4*)(bb2 + o4);
    float4 mm = *(const float4*)(m2 + o4);
    float4 vv = *(const float4*)(v2 + o4);
    float4 wo = *(const float4*)(Wlin + o4);
    float blin0 = blin[0];
    float4 sc;
    sc.x = gg.x * rsqrtf(vv.x + BN_EPS);
    sc.y = gg.y * rsqrtf(vv.y + BN_EPS);
    sc.z = gg.z * rsqrtf(vv.z + BN_EPS);
    sc.w = gg.w * rsqrtf(vv.w + BN_EPS);
#pragma unroll
    for (int j = 0; j < 4; j++) {
        float vx = fmaxf((acc[j].x + bl.x - mm.x) * sc.x + bb.x, 0.0f);
        float vy = fmaxf((acc[j].y + bl.y - mm.y) * sc.y + bb.y, 0.0f);
        float vz = fmaxf((acc[j].z + bl.z - mm.z) * sc.z + bb.z, 0.0f);
        float vw = fmaxf((acc[j].w + bl.w - mm.w) * sc.w + bb.w, 0.0f);
        float part = vx * wo.x + vy * wo.y + vz * wo.z + vw * wo.w;
#pragma unroll
        for (int m = 1; m < 16; m <<= 1) part += __shfl_xor(part, m, 64);
        if (lg == 0 && nbase + j < NN) out[nbase + j] = part + blin0;
    }
}

extern "C" void kernel_launch(void* const* d_in, const int* in_sizes, int n_in,
                              void* d_out, int out_size, void* d_ws, size_t ws_size,
                              hipStream_t stream) {
    const float* x    = (const float*)d_in[0];
    const int*   ei   = (const int*)d_in[1];
    const float* W1l  = (const float*)d_in[2];
    const float* b1l  = (const float*)d_in[3];
    const float* W1r  = (const float*)d_in[4];
    const float* g1   = (const float*)d_in[5];
    const float* bb1  = (const float*)d_in[6];
    const float* m1   = (const float*)d_in[7];
    const float* v1   = (const float*)d_in[8];
    const float* W2l  = (const float*)d_in[9];
    const float* b2l  = (const float*)d_in[10];
    const float* W2r  = (const float*)d_in[11];
    const float* g2   = (const float*)d_in[12];
    const float* bb2  = (const float*)d_in[13];
    const float* m2   = (const float*)d_in[14];
    const float* v2   = (const float*)d_in[15];
    const float* Wlin = (const float*)d_in[16];
    const float* blin = (const float*)d_in[17];
    float* out = (float*)d_out;

    // ws layout:
    //   cursor  int[256]          per-bucket claim cursors (only [0,196) used)
    //   region  u32[196*8192]     binned packed edges (6.4MB)
    //   deg_i   int[N]            degree per dst node (written by pass B)
    //   base    int[N]            row_end per node (written by pass B)
    //   csr16   ushort[E]         src indices sorted by dst
    //   aggb    bf16[64N]         aggregation buffer (bf16, reused both layers)
    //   h       bf16[64N]         layer-1 output (6.4MB)
    //   xb      bf16[32N]         x cast to bf16 (3.2MB)
    int* cursor = (int*)d_ws;
    unsigned int* region = (unsigned int*)(cursor + 256);
    int* deg_i = (int*)(region + (size_t)NBUCK * BCAP);
    int* base  = deg_i + NN;
    unsigned short* csr16 = (unsigned short*)(base + NN);
    unsigned short* aggb = csr16 + NE;
    unsigned short* h = aggb + (size_t)64 * NN;
    unsigned short* xb = h + (size_t)64 * NN;

    // only the bucket cursors need zeroing (1KB)
    hipMemsetAsync(cursor, 0, 256 * sizeof(int), stream);

    k_binA_cast<<<NAB + CASTB, 256, 0, stream>>>(ei, cursor, region, x, xb);
    k_binB<<<NBUCK, 256, 0, stream>>>(cursor, region, deg_i, base, csr16);

    k_gather32<<<(NN * 32 + 255) / 256, 256, 0, stream>>>(csr16, base, deg_i, xb, aggb);
    k_node1<<<NBLK, 256, 0, stream>>>(x, aggb, deg_i, W1l, b1l, W1r,
                                      g1, bb1, m1, v1, h);
    k_gather64<<<(NN * 64 + 255) / 256, 256, 0, stream>>>(csr16, base, deg_i, h, aggb);
    k_node2<<<NBLK, 256, 0, stream>>>(h, aggb, deg_i, W2l, b2l, W2r,
                                      g2, bb2, m2, v2, Wlin, blin, out);
}

// Round 17
// 192.271 us; speedup vs baseline: 1.0682x; 1.0547x over previous
//
#include <hip/hip_runtime.h>

// BusStopPredictor: 2x SAGEConv(mean) + BN(eval) + ReLU, then Linear(64->1).
// N=50000 nodes, E=800000 edges, 32 -> 64 -> 64 -> 1.
//
// Round 1: dst-sorted CSR + per-node gather (no float atomics): 1251 -> 374us.
// Round 2: node GEMMs 16-lanes-per-node: 374 -> 337us.
// Round 4: LDS weights + 4 nodes/thread; node1 full-unroll spilled: -> 371us.
// Round 5: unroll capped at 4 + gathers 2 edge-slots/node: -> 284us.
// Round 6: XCD-partitioned fill FAILED (chunk-claim barriers killed MLP).
// Round 7/9: uint16 csr + 4-slot gathers: -> 272us.
// Round 10: slice x range fill + NT: 269us (scatter write-back is structural).
// Round 11: two-pass LDS radix CSR build: 269 -> 214us.
// Round 12: fuse gather+node FAILED (255us, 18% occupancy + serial gather).
// Round 13/14: bf16-h: 214 -> 205us (h spills L2 -> byte-halving pays).
// Round 15: bf16-x gather32 NEUTRAL (x is L2-resident; cast cost cancelled).
// Round 16: agg bf16 + cast fused into binA: 205 -> 202.8us. Byte-shrinking
//   now exhausted (only L2-spilling streams pay).
// Round 17: gathers widened 4 -> 8 edge-slots (each ch-lane covers 8 ch via
//   uint4 16B loads; same coalescing, same bytes): halves the dependent
//   csr->row serial chain (4 -> 2 rounds at deg~16), 2x per-node TLP.
//   Attacks LATENCY, the only lever left in the gathers.

constexpr int NN = 50000;
constexpr int NE = 800000;
constexpr int NBLK = (NN + 63) / 64;    // 782 blocks, 64 nodes each
constexpr float BN_EPS = 1e-5f;

constexpr int NBUCK = 196;              // buckets of 256 nodes (dst>>8)
constexpr int BCAP  = 8192;             // per-bucket capacity (avg 4082)
constexpr int APB   = 2048;             // edges per pass-A block
constexpr int NAB   = (NE + APB - 1) / APB;  // 391
constexpr int CASTB = (NN * 32 / 8 + 255) / 256;  // 782 cast blocks

// fp32 -> bf16, round-to-nearest-even
__device__ __forceinline__ unsigned short f2bf(float f) {
    union { float f; unsigned int u; } c; c.f = f;
    unsigned int lsb = (c.u >> 16) & 1u;
    c.u += 0x7fffu + lsb;
    return (unsigned short)(c.u >> 16);
}
__device__ __forceinline__ unsigned int pack2bf(float a, float b) {
    return (unsigned int)f2bf(a) | ((unsigned int)f2bf(b) << 16);
}
__device__ __forceinline__ float bflo(unsigned int u) {
    return __uint_as_float(u << 16);
}
__device__ __forceinline__ float bfhi(unsigned int u) {
    return __uint_as_float(u & 0xffff0000u);
}

// ---------------- pass A: bin edges by dst>>8, + cast x->bf16 ----------------
// Blocks [0,NAB): bin packed (dst<<16|src) into per-bucket regions.
// Blocks [NAB,NAB+CASTB): cast x (fp32) -> xb (bf16), 8 elems/thread.
__global__ __launch_bounds__(256) void k_binA_cast(const int* __restrict__ ei,
                                                   int* __restrict__ cursor,
                                                   unsigned int* __restrict__ region,
                                                   const float* __restrict__ x,
                                                   unsigned short* __restrict__ xb) {
    __shared__ int lcnt[NBUCK];
    __shared__ int gb[NBUCK];
    int tid = threadIdx.x;

    if (blockIdx.x >= NAB) {   // cast role
        int i = ((blockIdx.x - NAB) * 256 + tid) * 8;
        if (i < NN * 32) {
            float4 a = *(const float4*)(x + i);
            float4 b = *(const float4*)(x + i + 4);
            ushort4 r0, r1;
            r0.x = f2bf(a.x); r0.y = f2bf(a.y); r0.z = f2bf(a.z); r0.w = f2bf(a.w);
            r1.x = f2bf(b.x); r1.y = f2bf(b.y); r1.z = f2bf(b.z); r1.w = f2bf(b.w);
            *(ushort4*)(xb + i) = r0;
            *(ushort4*)(xb + i + 4) = r1;
        }
        return;
    }

    for (int i = tid; i < NBUCK; i += 256) lcnt[i] = 0;
    __syncthreads();
    int e0 = blockIdx.x * APB;
    unsigned int pk[8];
    int bk[8], rk[8];
#pragma unroll
    for (int i = 0; i < 8; i++) {
        int e = e0 + i * 256 + tid;
        bk[i] = -1;
        if (e < NE) {
            int s = ei[e];
            int d = ei[NE + e];
            pk[i] = ((unsigned int)d << 16) | (unsigned int)s;
            bk[i] = d >> 8;
            rk[i] = atomicAdd(&lcnt[bk[i]], 1);
        }
    }
    __syncthreads();
    if (tid < NBUCK && lcnt[tid] > 0) gb[tid] = atomicAdd(&cursor[tid], lcnt[tid]);
    __syncthreads();
#pragma unroll
    for (int i = 0; i < 8; i++) {
        if (bk[i] >= 0) region[bk[i] * BCAP + gb[bk[i]] + rk[i]] = pk[i];
    }
}

// ---------------- pass B: build csr segment per bucket ----------------
__global__ __launch_bounds__(256) void k_binB(const int* __restrict__ cursor,
                                              const unsigned int* __restrict__ region,
                                              int* __restrict__ deg_i,
                                              int* __restrict__ base,
                                              unsigned short* __restrict__ csr16) {
    __shared__ unsigned int stg[BCAP];   // 32KB
    __shared__ int lc[256], cur[256], sctmp[256];
    int tid = threadIdx.x;
    int b = blockIdx.x;

    int cntt = (tid < NBUCK) ? cursor[tid] : 0;
    sctmp[tid] = cntt;
    __syncthreads();
    for (int off = 1; off < 256; off <<= 1) {
        int t = (tid >= off) ? sctmp[tid - off] : 0;
        __syncthreads();
        sctmp[tid] += t;
        __syncthreads();
    }
    int B0 = (b == 0) ? 0 : sctmp[b - 1];
    int mycnt = cursor[b];

    for (int k = tid; k < mycnt; k += 256) stg[k] = region[b * BCAP + k];
    lc[tid] = 0;
    __syncthreads();

    int node0 = b << 8;
    for (int k = tid; k < mycnt; k += 256) {
        int local = (int)(stg[k] >> 16) - node0;
        atomicAdd(&lc[local], 1);
    }
    __syncthreads();

    int myc = lc[tid];
    sctmp[tid] = myc;
    __syncthreads();
    for (int off = 1; off < 256; off <<= 1) {
        int t = (tid >= off) ? sctmp[tid - off] : 0;
        __syncthreads();
        sctmp[tid] += t;
        __syncthreads();
    }
    int myoff = sctmp[tid] - myc;
    cur[tid] = myoff;
    int n = node0 + tid;
    if (n < NN) {
        deg_i[n] = myc;
        base[n] = B0 + myoff + myc;   // row_end (gather contract)
    }
    __syncthreads();

    for (int k = tid; k < mycnt; k += 256) {
        unsigned int p = stg[k];
        int local = (int)(p >> 16) - node0;
        int pos = atomicAdd(&cur[local], 1);
        csr16[B0 + pos] = (unsigned short)(p & 0xffffu);
    }
}

// ---------------- gather aggregation, 32 channels (xb bf16 -> aggb bf16) ----
// 32 lanes per node: 8 edge-slots x 4 channel-lanes (8 ch each, uint4 16B).
// Serial chain deg/8 ~ 2 rounds. Merge via shfl_xor(4,8,16).
__global__ __launch_bounds__(256) void k_gather32(const unsigned short* __restrict__ csr_src,
                                                  const int* __restrict__ base,
                                                  const int* __restrict__ deg_i,
                                                  const unsigned short* __restrict__ xb,
                                                  unsigned short* __restrict__ aggb) {
    int t = blockIdx.x * 256 + threadIdx.x;
    int n = t >> 5;
    if (n >= NN) return;
    int p = (t >> 2) & 7;            // edge slot 0..7 (lane bits 2-4)
    int c8 = (t & 3) << 3;           // channel offset 0,8,16,24
    int end = base[n];
    int st = end - deg_i[n];
    float a0 = 0.f, a1 = 0.f, a2 = 0.f, a3 = 0.f;
    float a4 = 0.f, a5 = 0.f, a6 = 0.f, a7 = 0.f;
    for (int e = st + p; e < end; e += 8) {
        int s = csr_src[e];
        uint4 v = *(const uint4*)(xb + (size_t)s * 32 + c8);
        a0 += bflo(v.x); a1 += bfhi(v.x);
        a2 += bflo(v.y); a3 += bfhi(v.y);
        a4 += bflo(v.z); a5 += bfhi(v.z);
        a6 += bflo(v.w); a7 += bfhi(v.w);
    }
#pragma unroll
    for (int m = 4; m <= 16; m <<= 1) {
        a0 += __shfl_xor(a0, m, 64); a1 += __shfl_xor(a1, m, 64);
        a2 += __shfl_xor(a2, m, 64); a3 += __shfl_xor(a3, m, 64);
        a4 += __shfl_xor(a4, m, 64); a5 += __shfl_xor(a5, m, 64);
        a6 += __shfl_xor(a6, m, 64); a7 += __shfl_xor(a7, m, 64);
    }
    if (p == 0) {
        uint4 r;
        r.x = pack2bf(a0, a1); r.y = pack2bf(a2, a3);
        r.z = pack2bf(a4, a5); r.w = pack2bf(a6, a7);
        *(uint4*)(aggb + (size_t)n * 32 + c8) = r;
    }
}

// ---------------- gather aggregation, 64 channels (h bf16 -> aggb bf16) ----
// 64 lanes (full wave) per node: 8 edge-slots x 8 channel-lanes (8 ch each,
// uint4 16B). Per edge: 8 lanes x 16B = 128B coalesced row read.
// Serial chain deg/8 ~ 2 rounds. Merge via shfl_xor(8,16,32).
__global__ __launch_bounds__(256) void k_gather64(const unsigned short* __restrict__ csr_src,
                                                  const int* __restrict__ base,
                                                  const int* __restrict__ deg_i,
                                                  const unsigned short* __restrict__ h,
                                                  unsigned short* __restrict__ aggb) {
    int t = blockIdx.x * 256 + threadIdx.x;
    int n = t >> 6;
    if (n >= NN) return;
    int p = (t >> 3) & 7;            // edge slot 0..7 (lane bits 3-5)
    int c8 = (t & 7) << 3;           // channel offset 0,8,...,56
    int end = base[n];
    int st = end - deg_i[n];
    float a0 = 0.f, a1 = 0.f, a2 = 0.f, a3 = 0.f;
    float a4 = 0.f, a5 = 0.f, a6 = 0.f, a7 = 0.f;
    for (int e = st + p; e < end; e += 8) {
        int s = csr_src[e];
        uint4 v = *(const uint4*)(h + (size_t)s * 64 + c8);
        a0 += bflo(v.x); a1 += bfhi(v.x);
        a2 += bflo(v.y); a3 += bfhi(v.y);
        a4 += bflo(v.z); a5 += bfhi(v.z);
        a6 += bflo(v.w); a7 += bfhi(v.w);
    }
#pragma unroll
    for (int m = 8; m <= 32; m <<= 1) {
        a0 += __shfl_xor(a0, m, 64); a1 += __shfl_xor(a1, m, 64);
        a2 += __shfl_xor(a2, m, 64); a3 += __shfl_xor(a3, m, 64);
        a4 += __shfl_xor(a4, m, 64); a5 += __shfl_xor(a5, m, 64);
        a6 += __shfl_xor(a6, m, 64); a7 += __shfl_xor(a7, m, 64);
    }
    if (p == 0) {
        uint4 r;
        r.x = pack2bf(a0, a1); r.y = pack2bf(a2, a3);
        r.z = pack2bf(a4, a5); r.w = pack2bf(a6, a7);
        *(uint4*)(aggb + (size_t)n * 64 + c8) = r;
    }
}

// ---------------- node update layer 1 -> h (bf16) ----------------
// h = relu(bn1(aggb*deg_inv @ W1l + b1l + x @ W1r))
// Root term reads fp32 x (no bf16 error on that path). aggb read as bf16.
__global__ __launch_bounds__(256) void k_node1(
    const float* __restrict__ x, const unsigned short* __restrict__ aggb,
    const int* __restrict__ deg_i,
    const float* __restrict__ W1l, const float* __restrict__ b1l,
    const float* __restrict__ W1r,
    const float* __restrict__ g1, const float* __restrict__ bb1,
    const float* __restrict__ m1, const float* __restrict__ v1,
    unsigned short* __restrict__ h) {
    __shared__ float wlds[32 * 128];
    int tid = threadIdx.x;
    {
        const float4* l4 = (const float4*)W1l;   // 512 float4
        const float4* r4 = (const float4*)W1r;
        float4* s4 = (float4*)wlds;
#pragma unroll
        for (int i = 0; i < 2; i++) {
            int idx = tid + i * 256;
            int k = idx >> 4, c = idx & 15;
            s4[k * 32 + c] = l4[idx];
            s4[k * 32 + 16 + c] = r4[idx];
        }
    }
    __syncthreads();

    int lg = tid & 15, o4 = lg << 2;
    int nbase = blockIdx.x * 64 + (tid >> 4) * 4;
    if (nbase >= NN) return;

    float4 acc[4];
    float di[4];
    int nj[4];
#pragma unroll
    for (int j = 0; j < 4; j++) {
        acc[j] = make_float4(0.f, 0.f, 0.f, 0.f);
        nj[j] = min(nbase + j, NN - 1);   // clamp: loads stay in-bounds
        di[j] = 1.0f / fmaxf((float)deg_i[nj[j]], 1.0f);
    }

#pragma unroll 4
    for (int i4 = 0; i4 < 32; i4 += 4) {
        float4 wl[4], wr[4];
#pragma unroll
        for (int k = 0; k < 4; k++) {
            wl[k] = *(const float4*)&wlds[(i4 + k) * 128 + o4];
            wr[k] = *(const float4*)&wlds[(i4 + k) * 128 + 64 + o4];
        }
#pragma unroll
        for (int j = 0; j < 4; j++) {
            uint2 au = *(const uint2*)(aggb + (size_t)nj[j] * 32 + i4);
            float4 x4 = *(const float4*)(x + (size_t)nj[j] * 32 + i4);
            float av[4];
            av[0] = bflo(au.x) * di[j];
            av[1] = bfhi(au.x) * di[j];
            av[2] = bflo(au.y) * di[j];
            av[3] = bfhi(au.y) * di[j];
            float xv[4] = {x4.x, x4.y, x4.z, x4.w};
#pragma unroll
            for (int k = 0; k < 4; k++) {
                acc[j].x += av[k] * wl[k].x + xv[k] * wr[k].x;
                acc[j].y += av[k] * wl[k].y + xv[k] * wr[k].y;
                acc[j].z += av[k] * wl[k].z + xv[k] * wr[k].z;
                acc[j].w += av[k] * wl[k].w + xv[k] * wr[k].w;
            }
        }
    }

    float4 bl = *(const float4*)(b1l + o4);
    float4 gg = *(const float4*)(g1 + o4);
    float4 bb = *(const float4*)(bb1 + o4);
    float4 mm = *(const float4*)(m1 + o4);
    float4 vv = *(const float4*)(v1 + o4);
    float4 sc;
    sc.x = gg.x * rsqrtf(vv.x + BN_EPS);
    sc.y = gg.y * rsqrtf(vv.y + BN_EPS);
    sc.z = gg.z * rsqrtf(vv.z + BN_EPS);
    sc.w = gg.w * rsqrtf(vv.w + BN_EPS);
#pragma unroll
    for (int j = 0; j < 4; j++) {
        if (nbase + j >= NN) break;
        ushort4 r;
        r.x = f2bf(fmaxf((acc[j].x + bl.x - mm.x) * sc.x + bb.x, 0.0f));
        r.y = f2bf(fmaxf((acc[j].y + bl.y - mm.y) * sc.y + bb.y, 0.0f));
        r.z = f2bf(fmaxf((acc[j].z + bl.z - mm.z) * sc.z + bb.z, 0.0f));
        r.w = f2bf(fmaxf((acc[j].w + bl.w - mm.w) * sc.w + bb.w, 0.0f));
        *(ushort4*)(h + (size_t)(nbase + j) * 64 + o4) = r;
    }
}

// ---------------- node update layer 2 + final linear ----------------
// out = relu(bn2(aggb*deg_inv @ W2l + b2l + h @ W2r)) @ Wlin + blin
// h roots and aggb read as bf16.
__global__ __launch_bounds__(256) void k_node2(
    const unsigned short* __restrict__ h, const unsigned short* __restrict__ aggb,
    const int* __restrict__ deg_i,
    const float* __restrict__ W2l, const float* __restrict__ b2l,
    const float* __restrict__ W2r,
    const float* __restrict__ g2, const float* __restrict__ bb2,
    const float* __restrict__ m2, const float* __restrict__ v2,
    const float* __restrict__ Wlin, const float* __restrict__ blin,
    float* __restrict__ out) {
    __shared__ float wlds[64 * 128];
    int tid = threadIdx.x;
    {
        const float4* l4 = (const float4*)W2l;   // 1024 float4
        const float4* r4 = (const float4*)W2r;
        float4* s4 = (float4*)wlds;
#pragma unroll
        for (int i = 0; i < 4; i++) {
            int idx = tid + i * 256;
            int k = idx >> 4, c = idx & 15;
            s4[k * 32 + c] = l4[idx];
            s4[k * 32 + 16 + c] = r4[idx];
        }
    }
    __syncthreads();

    int lg = tid & 15, o4 = lg << 2;
    int nbase = blockIdx.x * 64 + (tid >> 4) * 4;
    if (nbase >= NN) return;

    float4 acc[4];
    float di[4];
    int nj[4];
#pragma unroll
    for (int j = 0; j < 4; j++) {
        acc[j] = make_float4(0.f, 0.f, 0.f, 0.f);
        nj[j] = min(nbase + j, NN - 1);
        di[j] = 1.0f / fmaxf((float)deg_i[nj[j]], 1.0f);
    }

#pragma unroll 4
    for (int i4 = 0; i4 < 64; i4 += 4) {
        float4 wl[4], wr[4];
#pragma unroll
        for (int k = 0; k < 4; k++) {
            wl[k] = *(const float4*)&wlds[(i4 + k) * 128 + o4];
            wr[k] = *(const float4*)&wlds[(i4 + k) * 128 + 64 + o4];
        }
#pragma unroll
        for (int j = 0; j < 4; j++) {
            uint2 au = *(const uint2*)(aggb + (size_t)nj[j] * 64 + i4);
            uint2 hu = *(const uint2*)(h + (size_t)nj[j] * 64 + i4);
            float av[4];
            av[0] = bflo(au.x) * di[j];
            av[1] = bfhi(au.x) * di[j];
            av[2] = bflo(au.y) * di[j];
            av[3] = bfhi(au.y) * di[j];
            float hv[4];
            hv[0] = bflo(hu.x);
            hv[1] = bfhi(hu.x);
            hv[2] = bflo(hu.y);
            hv[3] = bfhi(hu.y);
#pragma unroll
            for (int k = 0; k < 4; k++) {
                acc[j].x += av[k] * wl[k].x + hv[k] * wr[k].x;
                acc[j].y += av[k] * wl[k].y + hv[k] * wr[k].y;
                acc[j].z += av[k] * wl[k].z + hv[k] * wr[k].z;
                acc[j].w += av[k] * wl[k].w + hv[k] * wr[k].w;
            }
        }
    }

    float4 bl = *(const float4*)(b2l + o4);
    float4 gg = *(const float4*)(g2 + o4);
    float4 bb = *(const float4*)(bb2 + o4);
    float4 mm = *(const float4*)(m2 + o4);
    float4 vv = *(const float4*)(v2 + o4);
    float4 wo = *(const float4*)(Wlin + o4);
    float blin0 = blin[0];
    float4 sc;
    sc.x = gg.x * rsqrtf(vv.x + BN_EPS);
    sc.y = gg.y * rsqrtf(vv.y + BN_EPS);
    sc.z = gg.z * rsqrtf(vv.z + BN_EPS);
    sc.w = gg.w * rsqrtf(vv.w + BN_EPS);
#pragma unroll
    for (int j = 0; j < 4; j++) {
        float vx = fmaxf((acc[j].x + bl.x - mm.x) * sc.x + bb.x, 0.0f);
        float vy = fmaxf((acc[j].y + bl.y - mm.y) * sc.y + bb.y, 0.0f);
        float vz = fmaxf((acc[j].z + bl.z - mm.z) * sc.z + bb.z, 0.0f);
        float vw = fmaxf((acc[j].w + bl.w - mm.w) * sc.w + bb.w, 0.0f);
        float part = vx * wo.x + vy * wo.y + vz * wo.z + vw * wo.w;
#pragma unroll
        for (int m = 1; m < 16; m <<= 1) part += __shfl_xor(part, m, 64);
        if (lg == 0 && nbase + j < NN) out[nbase + j] = part + blin0;
    }
}

extern "C" void kernel_launch(void* const* d_in, const int* in_sizes, int n_in,
                              void* d_out, int out_size, void* d_ws, size_t ws_size,
                              hipStream_t stream) {
    const float* x    = (const float*)d_in[0];
    const int*   ei   = (const int*)d_in[1];
    const float* W1l  = (const float*)d_in[2];
    const float* b1l  = (const float*)d_in[3];
    const float* W1r  = (const float*)d_in[4];
    const float* g1   = (const float*)d_in[5];
    const float* bb1  = (const float*)d_in[6];
    const float* m1   = (const float*)d_in[7];
    const float* v1   = (const float*)d_in[8];
    const float* W2l  = (const float*)d_in[9];
    const float* b2l  = (const float*)d_in[10];
    const float* W2r  = (const float*)d_in[11];
    const float* g2   = (const float*)d_in[12];
    const float* bb2  = (const float*)d_in[13];
    const float* m2   = (const float*)d_in[14];
    const float* v2   = (const float*)d_in[15];
    const float* Wlin = (const float*)d_in[16];
    const float* blin = (const float*)d_in[17];
    float* out = (float*)d_out;

    // ws layout:
    //   cursor  int[256]          per-bucket claim cursors (only [0,196) used)
    //   region  u32[196*8192]     binned packed edges (6.4MB)
    //   deg_i   int[N]            degree per dst node (written by pass B)
    //   base    int[N]            row_end per node (written by pass B)
    //   csr16   ushort[E]         src indices sorted by dst
    //   aggb    bf16[64N]         aggregation buffer (bf16, reused both layers)
    //   h       bf16[64N]         layer-1 output (6.4MB)
    //   xb      bf16[32N]         x cast to bf16 (3.2MB)
    int* cursor = (int*)d_ws;
    unsigned int* region = (unsigned int*)(cursor + 256);
    int* deg_i = (int*)(region + (size_t)NBUCK * BCAP);
    int* base  = deg_i + NN;
    unsigned short* csr16 = (unsigned short*)(base + NN);
    unsigned short* aggb = csr16 + NE;
    unsigned short* h = aggb + (size_t)64 * NN;
    unsigned short* xb = h + (size_t)64 * NN;

    // only the bucket cursors need zeroing (1KB)
    hipMemsetAsync(cursor, 0, 256 * sizeof(int), stream);

    k_binA_cast<<<NAB + CASTB, 256, 0, stream>>>(ei, cursor, region, x, xb);
    k_binB<<<NBUCK, 256, 0, stream>>>(cursor, region, deg_i, base, csr16);

    k_gather32<<<(NN * 32 + 255) / 256, 256, 0, stream>>>(csr16, base, deg_i, xb, aggb);
    k_node1<<<NBLK, 256, 0, stream>>>(x, aggb, deg_i, W1l, b1l, W1r,
                                      g1, bb1, m1, v1, h);
    k_gather64<<<(NN * 64 + 255) / 256, 256, 0, stream>>>(csr16, base, deg_i, h, aggb);
    k_node2<<<NBLK, 256, 0, stream>>>(h, aggb, deg_i, W2l, b2l, W2r,
                                      g2, bb2, m2, v2, Wlin, blin, out);
}